// Round 1
// baseline (130.498 us; speedup 1.0000x reference)
//
#include <hip/hip_runtime.h>
#include <hip/hip_bf16.h>

// Curvature stencil: out = dxf/F - dxb/G + dyf/F - dyb/H over (B,H,W) fp32,
// reflect boundary (numpy/jnp 'reflect': index -1 -> 1, index N -> N-2).
// Layout: flat index = b*H*W + h*W + w, w contiguous.
//
// Per output (h,w) we need u at:
//   (h,w), (h+1,w), (h-1,w), (h,w+1), (h,w-1), (h-1,w+1), (h+1,w-1)
// i.e. rows h-1 (w..w+1), h (w-1..w+1), h+1 (w-1..w).
//
// Each thread computes 4 consecutive w via one float4 store; loads 3 aligned
// float4 (rows hm,h,hp) plus up to 4 edge scalars. Reflect at w-edges resolves
// to elements already inside the loaded float4 (reflect(-1)=1, reflect(W)=W-2).

#define Wdim 1024
#define Hdim 1024
#define EPSf 1e-16f

__global__ __launch_bounds__(256) void curv_kernel(const float* __restrict__ u,
                                                   float* __restrict__ out) {
    int t = blockIdx.x * blockDim.x + threadIdx.x;   // one float4 of output
    int q  = t & 255;            // float4 index within row (W/4 = 256)
    int w0 = q << 2;
    int h  = (t >> 8) & (Hdim - 1);
    int b  = t >> 18;

    const float* base = u + ((size_t)b << 20);       // b * H * W
    int hm = (h == 0)        ? 1        : h - 1;     // reflect
    int hp = (h == Hdim - 1) ? Hdim - 2 : h + 1;

    const float4* rowC = (const float4*)(base + (size_t)h  * Wdim);
    const float4* rowM = (const float4*)(base + (size_t)hm * Wdim);
    const float4* rowP = (const float4*)(base + (size_t)hp * Wdim);

    float4 c4 = rowC[q];
    float4 m4 = rowM[q];
    float4 p4 = rowP[q];

    // left neighbor (w0-1) for rows C and P
    float cl, pl;
    if (w0 == 0) { cl = c4.y; pl = p4.y; }           // reflect(-1) = 1
    else {
        cl = base[(size_t)h  * Wdim + w0 - 1];
        pl = base[(size_t)hp * Wdim + w0 - 1];
    }
    // right neighbor (w0+4) for rows C and M
    float cr, mr;
    if (w0 + 4 == Wdim) { cr = c4.z; mr = m4.z; }    // reflect(W) = W-2
    else {
        cr = base[(size_t)h  * Wdim + w0 + 4];
        mr = base[(size_t)hm * Wdim + w0 + 4];
    }

    float c[6] = {cl, c4.x, c4.y, c4.z, c4.w, cr};   // row h : w0-1 .. w0+4
    float m[5] = {m4.x, m4.y, m4.z, m4.w, mr};       // row hm: w0   .. w0+4
    float p[5] = {pl, p4.x, p4.y, p4.z, p4.w};       // row hp: w0-1 .. w0+3

    float4 o;
    float* op = &o.x;
#pragma unroll
    for (int j = 0; j < 4; ++j) {
        float cc   = c[j + 1];       // u[h, w]
        float cyp  = c[j + 2];       // u[h, w+1]
        float cym  = c[j];           // u[h, w-1]
        float mm   = m[j];           // u[h-1, w]
        float myp  = m[j + 1];       // u[h-1, w+1]
        float pp   = p[j + 1];       // u[h+1, w]
        float pym  = p[j];           // u[h+1, w-1]

        float dxf  = pp  - cc;
        float dxb  = cc  - mm;
        float dyf  = cyp - cc;
        float dyb  = cc  - cym;
        float dsbf = myp - mm;
        float dslf = pym - cym;

        float invF = rsqrtf(dxf * dxf + dyf * dyf + EPSf);
        float invG = rsqrtf(dxb * dxb + dsbf * dsbf + EPSf);
        float invH = rsqrtf(dslf * dslf + dyb * dyb + EPSf);

        op[j] = (dxf + dyf) * invF - dxb * invG - dyb * invH;
    }

    ((float4*)out)[t] = o;
}

extern "C" void kernel_launch(void* const* d_in, const int* in_sizes, int n_in,
                              void* d_out, int out_size, void* d_ws, size_t ws_size,
                              hipStream_t stream) {
    const float* u = (const float*)d_in[0];
    float* out = (float*)d_out;
    int total = in_sizes[0];                 // 16*1024*1024
    int n4 = total >> 2;                     // float4s
    int blocks = n4 / 256;                   // 16384
    curv_kernel<<<blocks, 256, 0, stream>>>(u, out);
}

// Round 2
// 121.592 us; speedup vs baseline: 1.0732x; 1.0732x over previous
//
#include <hip/hip_runtime.h>
#include <hip/hip_bf16.h>

// Curvature stencil, (16,1024,1024) fp32, reflect boundary.
// R2: 4-row x 4-col register tile per thread + XCD-aware block swizzle.
//   - Each thread loads 6 consecutive rows' float4 at its column (rows r0-1..r0+4,
//     reflected at image edges), plus left/right edge scalars (L1 hits), and
//     writes 4 float4 output rows. Vertical reuse now lives in registers.
//   - Block swizzle: hardware dispatches blockIdx round-robin over 8 XCDs; we
//     remap so each XCD processes a contiguous slab of rows in streaming order,
//     keeping the 3x row re-read inside the per-XCD 4 MiB L2.
//     grid = 4096 blocks; logical = ((idx&7)<<9) | (idx>>3).

#define Wdim 1024
#define Hdim 1024
#define EPSf 1e-16f

__global__ __launch_bounds__(256) void curv_kernel(const float* __restrict__ u,
                                                   float* __restrict__ out) {
    // swizzle: XCD (idx%8) gets contiguous logical range of 512 block-rows
    int blk = ((blockIdx.x & 7) << 9) | (blockIdx.x >> 3);
    int q  = threadIdx.x;            // float4 column, 0..255
    int w0 = q << 2;
    int rowBlk = blk & 255;          // 256 row-blocks of 4 rows per image
    int b      = blk >> 8;
    int r0     = rowBlk << 2;

    const float* base = u + ((size_t)b << 20);

    int rIdx[6];
    rIdx[0] = (r0 == 0) ? 1 : r0 - 1;            // reflect(-1)=1
    rIdx[1] = r0;
    rIdx[2] = r0 + 1;
    rIdx[3] = r0 + 2;
    rIdx[4] = r0 + 3;
    rIdx[5] = (r0 + 4 == Hdim) ? Hdim - 2 : r0 + 4;  // reflect(H)=H-2

    float4 R[6];
#pragma unroll
    for (int k = 0; k < 6; ++k)
        R[k] = ((const float4*)(base + (size_t)rIdx[k] * Wdim))[q];

    // left (w0-1) needed for rows k=1..5 (C and P of each output row),
    // right (w0+4) needed for rows k=0..4 (C and M). Edge columns reflect
    // into the already-loaded float4: reflect(-1)=1 -> .y, reflect(W)=W-2 -> .z.
    bool le = (w0 == 0), re = (w0 + 4 == Wdim);
    float Lv[6], Rv[6];
#pragma unroll
    for (int k = 1; k < 6; ++k)
        Lv[k] = le ? R[k].y : base[(size_t)rIdx[k] * Wdim + w0 - 1];
#pragma unroll
    for (int k = 0; k < 5; ++k)
        Rv[k] = re ? R[k].z : base[(size_t)rIdx[k] * Wdim + w0 + 4];

    size_t obase = ((size_t)b << 20) + (size_t)r0 * Wdim;
#pragma unroll
    for (int j = 0; j < 4; ++j) {
        const float4& C = R[1 + j];
        const float4& M = R[j];
        const float4& P = R[2 + j];
        float c[6] = {Lv[1 + j], C.x, C.y, C.z, C.w, Rv[1 + j]};
        float m[5] = {M.x, M.y, M.z, M.w, Rv[j]};
        float p[5] = {Lv[2 + j], P.x, P.y, P.z, P.w};

        float4 o;
        float* op = &o.x;
#pragma unroll
        for (int i = 0; i < 4; ++i) {
            float cc   = c[i + 1];
            float cyp  = c[i + 2];
            float cym  = c[i];
            float mm   = m[i];
            float myp  = m[i + 1];
            float pp   = p[i + 1];
            float pym  = p[i];

            float dxf  = pp  - cc;
            float dxb  = cc  - mm;
            float dyf  = cyp - cc;
            float dyb  = cc  - cym;
            float dsbf = myp - mm;
            float dslf = pym - cym;

            float invF = rsqrtf(dxf * dxf + dyf * dyf + EPSf);
            float invG = rsqrtf(dxb * dxb + dsbf * dsbf + EPSf);
            float invH = rsqrtf(dslf * dslf + dyb * dyb + EPSf);

            op[i] = (dxf + dyf) * invF - dxb * invG - dyb * invH;
        }
        ((float4*)(out + obase + (size_t)j * Wdim))[q] = o;
    }
}

extern "C" void kernel_launch(void* const* d_in, const int* in_sizes, int n_in,
                              void* d_out, int out_size, void* d_ws, size_t ws_size,
                              hipStream_t stream) {
    const float* u = (const float*)d_in[0];
    float* out = (float*)d_out;
    // 16 images * 256 row-blocks = 4096 blocks of 256 threads
    curv_kernel<<<4096, 256, 0, stream>>>(u, out);
}

// Round 4
// 111.069 us; speedup vs baseline: 1.1749x; 1.0947x over previous
//
#include <hip/hip_runtime.h>
#include <hip/hip_bf16.h>

// Curvature stencil, (16,1024,1024) fp32, reflect boundary.
// R4 = R3 with the nontemporal store fixed (clang native vec type, since
// __builtin_nontemporal_store rejects HIP_vector_type float4):
//   - 4x4 register tile per thread, XCD-aware block swizzle.
//   - Edge neighbors via wave shuffles (DS pipe) instead of scalar VMEM;
//     wave-boundary lanes 0/63 fall back to scalar load / edge reflect.
//   - Non-temporal float4 output stores (write-once stream, don't pollute L2).

#define Wdim 1024
#define Hdim 1024
#define EPSf 1e-16f

typedef float v4f __attribute__((ext_vector_type(4)));

__global__ __launch_bounds__(256) void curv_kernel(const float* __restrict__ u,
                                                   float* __restrict__ out) {
    // swizzle: XCD (idx%8) gets a contiguous slab of 512 block-rows
    int blk = ((blockIdx.x & 7) << 9) | (blockIdx.x >> 3);
    int q  = threadIdx.x;            // float4 column, 0..255
    int w0 = q << 2;
    int rowBlk = blk & 255;          // 256 row-blocks of 4 rows per image
    int b      = blk >> 8;
    int r0     = rowBlk << 2;

    const float* base = u + ((size_t)b << 20);

    int rIdx[6];
    rIdx[0] = (r0 == 0) ? 1 : r0 - 1;                // reflect(-1)=1
    rIdx[1] = r0;
    rIdx[2] = r0 + 1;
    rIdx[3] = r0 + 2;
    rIdx[4] = r0 + 3;
    rIdx[5] = (r0 + 4 == Hdim) ? Hdim - 2 : r0 + 4;  // reflect(H)=H-2

    v4f R[6];
#pragma unroll
    for (int k = 0; k < 6; ++k)
        R[k] = ((const v4f*)(base + (size_t)rIdx[k] * Wdim))[q];

    // Neighbors via shuffle: Lv[k] = lane-1's R[k].w, Rv[k] = lane+1's R[k].x
    float Lv[6], Rv[6];
#pragma unroll
    for (int k = 1; k < 6; ++k) Lv[k] = __shfl_up(R[k].w, 1);
#pragma unroll
    for (int k = 0; k < 5; ++k) Rv[k] = __shfl_down(R[k].x, 1);

    int lane = threadIdx.x & 63;
    if (lane == 0) {
        if (w0 == 0) {               // image left edge: reflect(-1)=1 -> .y
#pragma unroll
            for (int k = 1; k < 6; ++k) Lv[k] = R[k].y;
        } else {                     // wave boundary mid-row: scalar load
#pragma unroll
            for (int k = 1; k < 6; ++k)
                Lv[k] = base[(size_t)rIdx[k] * Wdim + w0 - 1];
        }
    }
    if (lane == 63) {
        if (w0 + 4 == Wdim) {        // image right edge: reflect(W)=W-2 -> .z
#pragma unroll
            for (int k = 0; k < 5; ++k) Rv[k] = R[k].z;
        } else {
#pragma unroll
            for (int k = 0; k < 5; ++k)
                Rv[k] = base[(size_t)rIdx[k] * Wdim + w0 + 4];
        }
    }

    size_t obase = ((size_t)b << 20) + (size_t)r0 * Wdim;
#pragma unroll
    for (int j = 0; j < 4; ++j) {
        v4f C = R[1 + j];
        v4f M = R[j];
        v4f P = R[2 + j];
        float c[6] = {Lv[1 + j], C.x, C.y, C.z, C.w, Rv[1 + j]};
        float m[5] = {M.x, M.y, M.z, M.w, Rv[j]};
        float p[5] = {Lv[2 + j], P.x, P.y, P.z, P.w};

        v4f o;
#pragma unroll
        for (int i = 0; i < 4; ++i) {
            float cc   = c[i + 1];
            float cyp  = c[i + 2];
            float cym  = c[i];
            float mm   = m[i];
            float myp  = m[i + 1];
            float pp   = p[i + 1];
            float pym  = p[i];

            float dxf  = pp  - cc;
            float dxb  = cc  - mm;
            float dyf  = cyp - cc;
            float dyb  = cc  - cym;
            float dsbf = myp - mm;
            float dslf = pym - cym;

            float invF = rsqrtf(dxf * dxf + dyf * dyf + EPSf);
            float invG = rsqrtf(dxb * dxb + dsbf * dsbf + EPSf);
            float invH = rsqrtf(dslf * dslf + dyb * dyb + EPSf);

            o[i] = (dxf + dyf) * invF - dxb * invG - dyb * invH;
        }
        __builtin_nontemporal_store(o, (v4f*)(out + obase + (size_t)j * Wdim) + q);
    }
}

extern "C" void kernel_launch(void* const* d_in, const int* in_sizes, int n_in,
                              void* d_out, int out_size, void* d_ws, size_t ws_size,
                              hipStream_t stream) {
    const float* u = (const float*)d_in[0];
    float* out = (float*)d_out;
    // 16 images * 256 row-blocks = 4096 blocks of 256 threads
    curv_kernel<<<4096, 256, 0, stream>>>(u, out);
}

// Round 5
// 108.770 us; speedup vs baseline: 1.1998x; 1.0211x over previous
//
#include <hip/hip_runtime.h>
#include <hip/hip_bf16.h>

// Curvature stencil, (16,1024,1024) fp32, reflect boundary.
// R5 = R4 with 8-row tiles (was 4):
//   - Each thread: 10 row float4 loads (rows r0-1..r0+8, reflected) ->
//     8 output rows. VMEM per output float4: 2.25 (was 2.5); vertical halo
//     amplification 1.25x (was 1.5x).
//   - Edge neighbors via wave shuffles; lanes 0/63 scalar-load fallback.
//   - Non-temporal output stores.
//   - Grid 2048 blocks; XCD swizzle: each XCD streams 256 contiguous
//     logical block-rows (2 images' worth).

#define Wdim 1024
#define Hdim 1024
#define EPSf 1e-16f
#define TR 8                         // tile rows

typedef float v4f __attribute__((ext_vector_type(4)));

__global__ __launch_bounds__(256) void curv_kernel(const float* __restrict__ u,
                                                   float* __restrict__ out) {
    int blk = ((blockIdx.x & 7) << 8) | (blockIdx.x >> 3);
    int q  = threadIdx.x;            // float4 column, 0..255
    int w0 = q << 2;
    int rowBlk = blk & 127;          // 128 row-blocks of 8 rows per image
    int b      = blk >> 7;
    int r0     = rowBlk << 3;

    const float* base = u + ((size_t)b << 20);

    int rIdx[TR + 2];
    rIdx[0] = (r0 == 0) ? 1 : r0 - 1;                    // reflect(-1)=1
#pragma unroll
    for (int k = 1; k <= TR; ++k) rIdx[k] = r0 + k - 1;
    rIdx[TR + 1] = (r0 + TR == Hdim) ? Hdim - 2 : r0 + TR;  // reflect(H)=H-2

    v4f R[TR + 2];
#pragma unroll
    for (int k = 0; k < TR + 2; ++k)
        R[k] = ((const v4f*)(base + (size_t)rIdx[k] * Wdim))[q];

    // Neighbors via shuffle: Lv[k] = lane-1's R[k].w, Rv[k] = lane+1's R[k].x
    float Lv[TR + 2], Rv[TR + 2];
#pragma unroll
    for (int k = 1; k < TR + 2; ++k) Lv[k] = __shfl_up(R[k].w, 1);
#pragma unroll
    for (int k = 0; k < TR + 1; ++k) Rv[k] = __shfl_down(R[k].x, 1);

    int lane = threadIdx.x & 63;
    if (lane == 0) {
        if (w0 == 0) {               // image left edge: reflect(-1)=1 -> .y
#pragma unroll
            for (int k = 1; k < TR + 2; ++k) Lv[k] = R[k].y;
        } else {                     // wave boundary mid-row: scalar load
#pragma unroll
            for (int k = 1; k < TR + 2; ++k)
                Lv[k] = base[(size_t)rIdx[k] * Wdim + w0 - 1];
        }
    }
    if (lane == 63) {
        if (w0 + 4 == Wdim) {        // image right edge: reflect(W)=W-2 -> .z
#pragma unroll
            for (int k = 0; k < TR + 1; ++k) Rv[k] = R[k].z;
        } else {
#pragma unroll
            for (int k = 0; k < TR + 1; ++k)
                Rv[k] = base[(size_t)rIdx[k] * Wdim + w0 + 4];
        }
    }

    size_t obase = ((size_t)b << 20) + (size_t)r0 * Wdim;
#pragma unroll
    for (int j = 0; j < TR; ++j) {
        v4f C = R[1 + j];
        v4f M = R[j];
        v4f P = R[2 + j];
        float c[6] = {Lv[1 + j], C.x, C.y, C.z, C.w, Rv[1 + j]};
        float m[5] = {M.x, M.y, M.z, M.w, Rv[j]};
        float p[5] = {Lv[2 + j], P.x, P.y, P.z, P.w};

        v4f o;
#pragma unroll
        for (int i = 0; i < 4; ++i) {
            float cc   = c[i + 1];
            float cyp  = c[i + 2];
            float cym  = c[i];
            float mm   = m[i];
            float myp  = m[i + 1];
            float pp   = p[i + 1];
            float pym  = p[i];

            float dxf  = pp  - cc;
            float dxb  = cc  - mm;
            float dyf  = cyp - cc;
            float dyb  = cc  - cym;
            float dsbf = myp - mm;
            float dslf = pym - cym;

            float invF = rsqrtf(dxf * dxf + dyf * dyf + EPSf);
            float invG = rsqrtf(dxb * dxb + dsbf * dsbf + EPSf);
            float invH = rsqrtf(dslf * dslf + dyb * dyb + EPSf);

            o[i] = (dxf + dyf) * invF - dxb * invG - dyb * invH;
        }
        __builtin_nontemporal_store(o, (v4f*)(out + obase + (size_t)j * Wdim) + q);
    }
}

extern "C" void kernel_launch(void* const* d_in, const int* in_sizes, int n_in,
                              void* d_out, int out_size, void* d_ws, size_t ws_size,
                              hipStream_t stream) {
    const float* u = (const float*)d_in[0];
    float* out = (float*)d_out;
    // 16 images * 128 row-blocks = 2048 blocks of 256 threads
    curv_kernel<<<2048, 256, 0, stream>>>(u, out);
}